// Round 1
// baseline (821.859 us; speedup 1.0000x reference)
//
#include <hip/hip_runtime.h>

#define H 128

typedef float v4f __attribute__((ext_vector_type(4)));
typedef short v8s __attribute__((ext_vector_type(8)));

// ---------------- bf16 helpers ----------------

__device__ inline unsigned short bf16_rne(float x) {
  unsigned u = __builtin_bit_cast(unsigned, x);
  unsigned r = u + 0x7FFF + ((u >> 16) & 1);
  return (unsigned short)(r >> 16);
}

__device__ inline void split_bf16(float x, unsigned short& hi, unsigned short& lo) {
  unsigned u = __builtin_bit_cast(unsigned, x);
  unsigned r = u + 0x7FFF + ((u >> 16) & 1);  // RNE round to bf16
  hi = (unsigned short)(r >> 16);
  float hf = __builtin_bit_cast(float, r & 0xFFFF0000u);
  float d = x - hf;
  unsigned ud = __builtin_bit_cast(unsigned, d);
  unsigned rd = ud + 0x7FFF + ((ud >> 16) & 1);
  lo = (unsigned short)(rd >> 16);
}

// ---------------- CSR build (unchanged) ----------------

__global__ void hist_kernel(const int* __restrict__ dst, int* __restrict__ deg, int E) {
  int e = blockIdx.x * 256 + threadIdx.x;
  if (e < E) atomicAdd(&deg[dst[e]], 1);
}

__global__ __launch_bounds__(1024) void scan1_kernel(const int* __restrict__ deg,
                                                     int* __restrict__ incl,
                                                     int* __restrict__ blk_sum, int N) {
  __shared__ int lds[1024];
  int t = threadIdx.x;
  int i = blockIdx.x * 1024 + t;
  int v = (i < N) ? deg[i] : 0;
  lds[t] = v;
  __syncthreads();
  for (int off = 1; off < 1024; off <<= 1) {
    int x = (t >= off) ? lds[t - off] : 0;
    __syncthreads();
    lds[t] += x;
    __syncthreads();
  }
  if (i < N) incl[i] = lds[t];
  if (t == 1023) blk_sum[blockIdx.x] = lds[1023];
}

__global__ void scan2_kernel(const int* __restrict__ blk_sum, int* __restrict__ blk_off, int B) {
  __shared__ int lds[256];
  int t = threadIdx.x;
  int v = (t < B) ? blk_sum[t] : 0;
  lds[t] = v;
  __syncthreads();
  for (int off = 1; off < 256; off <<= 1) {
    int x = (t >= off) ? lds[t - off] : 0;
    __syncthreads();
    lds[t] += x;
    __syncthreads();
  }
  blk_off[t] = lds[t] - v;  // exclusive scan of block sums
}

__global__ void rowstart_kernel(const int* __restrict__ incl, const int* __restrict__ deg,
                                const int* __restrict__ blk_off, int* __restrict__ row_start,
                                int N) {
  int i = blockIdx.x * 256 + threadIdx.x;
  if (i < N) row_start[i] = blk_off[i >> 10] + incl[i] - deg[i];
}

__global__ void fill_kernel(const int* __restrict__ src, const int* __restrict__ dst,
                            const int* __restrict__ row_start, int* __restrict__ cursor,
                            int* __restrict__ csr_src, int E) {
  int e = blockIdx.x * 256 + threadIdx.x;
  if (e < E) {
    int d = dst[e];
    int p = atomicAdd(&cursor[d], 1);
    csr_src[row_start[d] + p] = src[e];
  }
}

// ---------------- feature gather: emb -> bf16 hi/lo planes ----------------
// All activations live as two row-major [N][128] bf16 planes (hi, lo).
// hi == bf16_rne(fp32 value), lo == bf16_rne(value - hi): identical to the
// previous kernel's in-GEMM split, so numerics are bit-identical.

__global__ void gather_kernel(const float* __restrict__ emb, const int* __restrict__ node_id,
                              unsigned short* __restrict__ h_hi, unsigned short* __restrict__ h_lo,
                              int N) {
  int i = blockIdx.x * 256 + threadIdx.x;
  if (i < N * 32) {
    int n = i >> 5, g = i & 31;
    float4 v = ((const float4*)emb)[(size_t)node_id[n] * 32 + g];
    float vv[4] = {v.x, v.y, v.z, v.w};
    unsigned short hs[4], ls[4];
#pragma unroll
    for (int k = 0; k < 4; ++k) split_bf16(vv[k], hs[k], ls[k]);
    size_t base = (size_t)n * H + g * 4;
    *(uint2*)(h_hi + base) = make_uint2((unsigned)hs[0] | ((unsigned)hs[1] << 16),
                                        (unsigned)hs[2] | ((unsigned)hs[3] << 16));
    *(uint2*)(h_lo + base) = make_uint2((unsigned)ls[0] | ((unsigned)ls[1] << 16),
                                        (unsigned)ls[2] | ((unsigned)ls[3] << 16));
  }
}

// ---------------- weight pre-split into MFMA-frag-ordered planes ----------------
// Frag order per plane (16384 shorts): e = c*2048 + kb*512 + q*128 + m*8 + j
// holds W[col = c*16+m][k = kb*32 + q*8 + j]. A wave's 64 lanes then read one
// frag as a stride-1 ds_read_b128 (conflict-free). Buffer layout:
// Wf[layer][side l/r][hi,lo][16384], layer stride 65536 shorts.

__global__ void wsplit_kernel(const float* __restrict__ W0, const float* __restrict__ W1,
                              const float* __restrict__ W2, const float* __restrict__ W3,
                              const float* __restrict__ W4, const float* __restrict__ W5,
                              unsigned short* __restrict__ Wf) {
  int idx = blockIdx.x * 256 + threadIdx.x;  // 0..98303 (6 planes x 16384)
  int sp = idx >> 14;                        // {W1l,W1r,W2l,W2r,W3l,W3r}
  int e = idx & 16383;
  const float* src = sp == 0 ? W0 : sp == 1 ? W1 : sp == 2 ? W2
                   : sp == 3 ? W3 : sp == 4 ? W4 : W5;
  int c = e >> 11;
  int kb = (e >> 9) & 3;
  int qq = (e >> 7) & 3;
  int mm = (e >> 3) & 15;
  int j = e & 7;
  int col = c * 16 + mm;
  int k = kb * 32 + qq * 8 + j;
  unsigned short hi, lo;
  split_bf16(src[col * H + k], hi, lo);
  size_t base = (size_t)(sp >> 1) * 65536 + (size_t)(sp & 1) * 32768 + e;
  Wf[base] = hi;          // hi plane
  Wf[base + 16384] = lo;  // lo plane
}

// ---------------- mean aggregation (CSR, bf16 gather, split-plane output) ----------------

__global__ __launch_bounds__(256) void aggregate_kernel(const unsigned short* __restrict__ hb,
                                                        const int* __restrict__ csr_src,
                                                        const int* __restrict__ row_start,
                                                        const int* __restrict__ deg,
                                                        unsigned short* __restrict__ a_hi,
                                                        unsigned short* __restrict__ a_lo, int N) {
  int node = blockIdx.x * 4 + (threadIdx.x >> 6);
  if (node >= N) return;
  int lane = threadIdx.x & 63;
  int qe = lane >> 4;  // edge slot 0..3
  int cl = lane & 15;  // channel group: channels cl*8 .. cl*8+7
  const uint4* __restrict__ h16 = (const uint4*)hb;

  int start = row_start[node];
  int d = deg[node];

  float acc[8] = {0.f, 0.f, 0.f, 0.f, 0.f, 0.f, 0.f, 0.f};

  auto accum = [&](uint4 u) {
    unsigned uu[4] = {u.x, u.y, u.z, u.w};
#pragma unroll
    for (int j = 0; j < 4; ++j) {
      acc[2 * j] += __builtin_bit_cast(float, uu[j] << 16);
      acc[2 * j + 1] += __builtin_bit_cast(float, uu[j] & 0xFFFF0000u);
    }
  };

  int e = qe;
  for (; e + 4 < d; e += 8) {
    int s0 = csr_src[start + e];
    int s1 = csr_src[start + e + 4];
    uint4 u0 = h16[(size_t)s0 * 16 + cl];
    uint4 u1 = h16[(size_t)s1 * 16 + cl];
    accum(u0);
    accum(u1);
  }
  for (; e < d; e += 4) {
    int s = csr_src[start + e];
    accum(h16[(size_t)s * 16 + cl]);
  }

#pragma unroll
  for (int j = 0; j < 8; ++j) {
    acc[j] += __shfl_xor(acc[j], 16);
    acc[j] += __shfl_xor(acc[j], 32);
  }

  float inv = 1.0f / fmaxf((float)d, 1.0f);
  if (qe < 2) {
    unsigned short hs[4], ls[4];
    int b = qe * 4;
#pragma unroll
    for (int j = 0; j < 4; ++j) split_bf16(acc[b + j] * inv, hs[j], ls[j]);
    size_t o = (size_t)node * H + cl * 8 + qe * 4;
    *(uint2*)(a_hi + o) = make_uint2((unsigned)hs[0] | ((unsigned)hs[1] << 16),
                                     (unsigned)hs[2] | ((unsigned)hs[3] << 16));
    *(uint2*)(a_lo + o) = make_uint2((unsigned)ls[0] | ((unsigned)ls[1] << 16),
                                     (unsigned)ls[2] | ((unsigned)ls[3] << 16));
  }
}

// ---------------- weights-stationary barrier-free dual-GEMM ----------------
// All 4 W planes (Wl_hi, Wl_lo, Wr_hi, Wr_lo = 128 KiB) in LDS, loaded once.
// 512 threads (8 waves), 1 block/CU, grid = 256. Each wave streams 16-row
// tiles grabbed from a global atomic counter, A-frags loaded straight from
// global (pre-split planes, frag layout == row-major 16B slices), double-
// buffered tile prefetch, no __syncthreads in the main loop.
// GEMM is row-local (reads aggr[r], h[r]; writes out[r]) so output may
// alias the aggr planes (in-place).

template <int RELU, int FINAL>
__global__ __launch_bounds__(512, 2) void gemm_ws(
    const unsigned short* ag_hi, const unsigned short* ag_lo,
    const unsigned short* h_hi, const unsigned short* h_lo,
    const unsigned short* __restrict__ Wfrag, const float* __restrict__ bias,
    unsigned short* out_hi, unsigned short* out_lo, float* __restrict__ outf,
    int* __restrict__ tcnt, int N) {
  extern __shared__ unsigned short Wsh[];  // 65536 shorts = 128 KiB
  int tid = threadIdx.x;
  {  // cooperative W load: 8192 x 16 B
    const v8s* gs = (const v8s*)Wfrag;
    v8s* ls = (v8s*)Wsh;
#pragma unroll
    for (int i = 0; i < 16; ++i) ls[tid + i * 512] = gs[tid + i * 512];
  }
  int lane = tid & 63;
  int m = lane & 15, q = lane >> 4;
  float bv[8];
#pragma unroll
  for (int c = 0; c < 8; ++c) bv[c] = bias[c * 16 + m];
  __syncthreads();  // the only barrier

  const v8s* WF = (const v8s*)Wsh;
  int nT = (N + 15) >> 4;

  auto grab = [&]() {
    int t = 0;
    if (lane == 0) t = atomicAdd(tcnt, 1);
    return __shfl(t, 0);
  };

  // a[0..3]=aggr_hi kb0..3, a[4..7]=aggr_lo, a[8..11]=h_hi, a[12..15]=h_lo
  auto loadA = [&](v8s (&a)[16], int t) {
    int rr = t * 16 + m;
    if (rr >= N) rr = N - 1;
    const unsigned short* p0 = ag_hi + (size_t)rr * H + q * 8;
    const unsigned short* p1 = ag_lo + (size_t)rr * H + q * 8;
    const unsigned short* p2 = h_hi + (size_t)rr * H + q * 8;
    const unsigned short* p3 = h_lo + (size_t)rr * H + q * 8;
#pragma unroll
    for (int kb = 0; kb < 4; ++kb) {
      a[kb] = *(const v8s*)(p0 + kb * 32);
      a[4 + kb] = *(const v8s*)(p1 + kb * 32);
      a[8 + kb] = *(const v8s*)(p2 + kb * 32);
      a[12 + kb] = *(const v8s*)(p3 + kb * 32);
    }
  };

  auto computeStore = [&](const v8s (&a)[16], int t) {
    v4f acc[8];
#pragma unroll
    for (int c = 0; c < 8; ++c) acc[c] = (v4f){0.f, 0.f, 0.f, 0.f};
#pragma unroll
    for (int s = 0; s < 2; ++s) {  // side 0: aggr@Wl, side 1: h@Wr
#pragma unroll
      for (int kb = 0; kb < 4; ++kb) {
        v8s ah = a[s * 8 + kb];
        v8s al = a[s * 8 + 4 + kb];
#pragma unroll
        for (int c = 0; c < 8; ++c) {
          v8s bh = WF[s * 4096 + c * 256 + kb * 64 + lane];
          v8s bl = WF[s * 4096 + 2048 + c * 256 + kb * 64 + lane];
          acc[c] = __builtin_amdgcn_mfma_f32_16x16x32_bf16(ah, bh, acc[c], 0, 0, 0);
          acc[c] = __builtin_amdgcn_mfma_f32_16x16x32_bf16(al, bh, acc[c], 0, 0, 0);
          acc[c] = __builtin_amdgcn_mfma_f32_16x16x32_bf16(ah, bl, acc[c], 0, 0, 0);
        }
      }
    }
#pragma unroll
    for (int c = 0; c < 8; ++c) {
#pragma unroll
      for (int i = 0; i < 4; ++i) {
        int r = t * 16 + q * 4 + i;
        if (r < N) {
          float v = acc[c][i] + bv[c];
          if (RELU) v = fmaxf(v, 0.f);
          size_t o = (size_t)r * H + c * 16 + m;
          if (FINAL) {
            outf[o] = v;
          } else {
            unsigned short hi, lo;
            split_bf16(v, hi, lo);
            out_hi[o] = hi;
            out_lo[o] = lo;
          }
        }
      }
    }
  };

  v8s A0[16], A1[16];  // named double buffers: all indexing compile-time
  int tc = grab();
  if (tc >= nT) return;
  loadA(A0, tc);
  int tn = grab();
  if (tn < nT) loadA(A1, tn);
  while (true) {
    computeStore(A0, tc);
    if (tn >= nT) return;
    tc = tn;
    tn = grab();
    if (tn < nT) loadA(A0, tn);  // prefetch before computing A1
    computeStore(A1, tc);
    if (tn >= nT) return;
    tc = tn;
    tn = grab();
    if (tn < nT) loadA(A1, tn);  // prefetch before computing A0
  }
}

// ---------------- launch ----------------

extern "C" void kernel_launch(void* const* d_in, const int* in_sizes, int n_in,
                              void* d_out, int out_size, void* d_ws, size_t ws_size,
                              hipStream_t stream) {
  const int* node_id = (const int*)d_in[0];
  const int* edge_index = (const int*)d_in[1];
  const float* emb = (const float*)d_in[2];
  const float* W1l = (const float*)d_in[3];
  const float* b1l = (const float*)d_in[4];
  const float* W1r = (const float*)d_in[5];
  const float* W2l = (const float*)d_in[6];
  const float* b2l = (const float*)d_in[7];
  const float* W2r = (const float*)d_in[8];
  const float* W3l = (const float*)d_in[9];
  const float* b3l = (const float*)d_in[10];
  const float* W3r = (const float*)d_in[11];

  int N = in_sizes[0];
  int E = in_sizes[1] / 2;
  const int* src = edge_index;
  const int* dst = edge_index + E;

  char* w = (char*)d_ws;
  auto alloc = [&](size_t bytes) {
    void* p = (void*)w;
    w += (bytes + 255) & ~(size_t)255;
    return p;
  };
  int* deg = (int*)alloc((size_t)N * 4);
  int* cursor = (int*)alloc((size_t)N * 4);
  int* row_start = (int*)alloc((size_t)N * 4);
  int* incl = (int*)alloc((size_t)N * 4);
  int* blk_sum = (int*)alloc(1024);
  int* blk_off = (int*)alloc(1024);
  int* csr_src = (int*)alloc((size_t)E * 4);
  int* tcnt = (int*)alloc(256);  // 3 work-steal counters
  unsigned short* P0h = (unsigned short*)alloc((size_t)N * H * 2);
  unsigned short* P0l = (unsigned short*)alloc((size_t)N * H * 2);
  unsigned short* P1h = (unsigned short*)alloc((size_t)N * H * 2);
  unsigned short* P1l = (unsigned short*)alloc((size_t)N * H * 2);
  unsigned short* Wf = (unsigned short*)alloc((size_t)3 * 65536 * 2);

  static int attr_done = 0;
  if (!attr_done) {
    hipFuncSetAttribute(reinterpret_cast<const void*>(&gemm_ws<1, 0>),
                        hipFuncAttributeMaxDynamicSharedMemorySize, 131072);
    hipFuncSetAttribute(reinterpret_cast<const void*>(&gemm_ws<0, 1>),
                        hipFuncAttributeMaxDynamicSharedMemorySize, 131072);
    attr_done = 1;
  }

  hipMemsetAsync(deg, 0, (size_t)N * 4, stream);
  hipMemsetAsync(cursor, 0, (size_t)N * 4, stream);
  hipMemsetAsync(tcnt, 0, 256, stream);

  hist_kernel<<<(E + 255) / 256, 256, 0, stream>>>(dst, deg, E);
  int SB = (N + 1023) / 1024;
  scan1_kernel<<<SB, 1024, 0, stream>>>(deg, incl, blk_sum, N);
  scan2_kernel<<<1, 256, 0, stream>>>(blk_sum, blk_off, SB);
  rowstart_kernel<<<(N + 255) / 256, 256, 0, stream>>>(incl, deg, blk_off, row_start, N);
  fill_kernel<<<(E + 255) / 256, 256, 0, stream>>>(src, dst, row_start, cursor, csr_src, E);

  gather_kernel<<<(N * 32 + 255) / 256, 256, 0, stream>>>(emb, node_id, P0h, P0l, N);
  wsplit_kernel<<<384, 256, 0, stream>>>(W1l, W1r, W2l, W2r, W3l, W3r, Wf);

  int gag = (N + 3) / 4;

  // layer 1: h1 = P0; aggr1 -> P1; gemm writes in-place over P1 => h2 = P1
  aggregate_kernel<<<gag, 256, 0, stream>>>(P0h, csr_src, row_start, deg, P1h, P1l, N);
  gemm_ws<1, 0><<<256, 512, 131072, stream>>>(P1h, P1l, P0h, P0l, Wf, b1l,
                                              P1h, P1l, nullptr, tcnt, N);

  // layer 2: aggr2 -> P0 (over dead h1); gemm in-place over P0 => h3 = P0
  aggregate_kernel<<<gag, 256, 0, stream>>>(P1h, csr_src, row_start, deg, P0h, P0l, N);
  gemm_ws<1, 0><<<256, 512, 131072, stream>>>(P0h, P0l, P1h, P1l, Wf + 65536, b2l,
                                              P0h, P0l, nullptr, tcnt + 1, N);

  // layer 3: aggr3 -> P1 (over dead h2); final gemm -> fp32 d_out
  aggregate_kernel<<<gag, 256, 0, stream>>>(P0h, csr_src, row_start, deg, P1h, P1l, N);
  gemm_ws<0, 1><<<256, 512, 131072, stream>>>(P1h, P1l, P0h, P0l, Wf + 131072, b3l,
                                              nullptr, nullptr, (float*)d_out, tcnt + 2, N);
}